// Round 1
// baseline (484.929 us; speedup 1.0000x reference)
//
#include <hip/hip_runtime.h>

// ---------------------------------------------------------------------------
// Fused causal attention, MI355X gfx950.
// Pipeline: cast fp32->f16, QKV GEMM (f16 MFMA), flash attention (f16 MFMA),
// output GEMM (f16 MFMA, fp32 out).
// MFMA 16x16x32 layouts (m89/m91/m120-verified):
//   A-frag: A[m=lane&15][k=(lane>>4)*8+j], j=0..7  (8 f16, contiguous in k)
//   B-frag: B[k=(lane>>4)*8+j][n=lane&15]          (contiguous in k)
//   C/D   : row=(lane>>4)*4+reg, col=lane&15
// ---------------------------------------------------------------------------

typedef _Float16 f16x8 __attribute__((ext_vector_type(8)));
typedef float floatx4 __attribute__((ext_vector_type(4)));

union U4H8 { uint4 u; f16x8 h; };

__device__ __forceinline__ ushort f32_to_h_bits(float f) {
  _Float16 h = (_Float16)f;
  return __builtin_bit_cast(ushort, h);
}

// ---------------------------------------------------------------- cast kernel
__global__ __launch_bounds__(256) void cast_f32_f16(const float* __restrict__ in,
                                                    ushort* __restrict__ out) {
  int i = blockIdx.x * 256 + threadIdx.x;  // 4 elems/thread, n % 1024 == 0
  float4 v = ((const float4*)in)[i];
  ushort4 o;
  o.x = f32_to_h_bits(v.x);
  o.y = f32_to_h_bits(v.y);
  o.z = f32_to_h_bits(v.z);
  o.w = f32_to_h_bits(v.w);
  ((ushort4*)out)[i] = o;
}

// ------------------------------------------------------------------ GEMM B^T
// C[M,N] = A[M,K] * B[N,K]^T.  f16 in, f16 or f32 out.
// 128x128 tile, BK=32, 256 threads = 4 waves in 2x2, each wave 64x64 (4x4 MFMA).
template <int OUT_F16>
__global__ __launch_bounds__(256) void gemm_bt(const ushort* __restrict__ A,
                                               const ushort* __restrict__ B,
                                               void* __restrict__ Cv,
                                               int M, int N, int K) {
  __shared__ ushort As[128 * 32];  // unpadded: frag reads cover contiguous 1KB -> optimal
  __shared__ ushort Bs[128 * 32];

  const int tid = threadIdx.x;
  const int lane = tid & 63;
  const int wid = tid >> 6;
  const int l15 = lane & 15;
  const int quad = lane >> 4;
  const int m0 = blockIdx.y * 128;
  const int n0 = blockIdx.x * 128;
  const int wm = (wid & 1) * 64;
  const int wn = (wid >> 1) * 64;

  floatx4 acc[4][4];
#pragma unroll
  for (int i = 0; i < 4; i++)
#pragma unroll
    for (int j = 0; j < 4; j++) acc[i][j] = (floatx4){0.f, 0.f, 0.f, 0.f};

  const int srow = tid >> 2;        // 0..63 (and +64 for 2nd vector)
  const int scol = (tid & 3) * 8;   // 0,8,16,24
  const ushort* Ap0 = A + (size_t)(m0 + srow) * K + scol;
  const ushort* Ap1 = A + (size_t)(m0 + 64 + srow) * K + scol;
  const ushort* Bp0 = B + (size_t)(n0 + srow) * K + scol;
  const ushort* Bp1 = B + (size_t)(n0 + 64 + srow) * K + scol;
  ushort* As0 = &As[srow * 32 + scol];
  ushort* As1 = &As[(srow + 64) * 32 + scol];
  ushort* Bs0 = &Bs[srow * 32 + scol];
  ushort* Bs1 = &Bs[(srow + 64) * 32 + scol];

  for (int k0 = 0; k0 < K; k0 += 32) {
    uint4 a0 = *(const uint4*)(Ap0 + k0);
    uint4 a1 = *(const uint4*)(Ap1 + k0);
    uint4 b0 = *(const uint4*)(Bp0 + k0);
    uint4 b1 = *(const uint4*)(Bp1 + k0);
    __syncthreads();  // previous iteration's reads must finish before overwrite
    *(uint4*)As0 = a0;
    *(uint4*)As1 = a1;
    *(uint4*)Bs0 = b0;
    *(uint4*)Bs1 = b1;
    __syncthreads();

    U4H8 af[4], bf[4];
#pragma unroll
    for (int mi = 0; mi < 4; mi++)
      af[mi].u = *(const uint4*)&As[(wm + mi * 16 + l15) * 32 + quad * 8];
#pragma unroll
    for (int ni = 0; ni < 4; ni++)
      bf[ni].u = *(const uint4*)&Bs[(wn + ni * 16 + l15) * 32 + quad * 8];
#pragma unroll
    for (int mi = 0; mi < 4; mi++)
#pragma unroll
      for (int ni = 0; ni < 4; ni++)
        acc[mi][ni] = __builtin_amdgcn_mfma_f32_16x16x32_f16(af[mi].h, bf[ni].h,
                                                             acc[mi][ni], 0, 0, 0);
  }

#pragma unroll
  for (int mi = 0; mi < 4; mi++) {
#pragma unroll
    for (int r = 0; r < 4; r++) {
      size_t row = m0 + wm + mi * 16 + quad * 4 + r;
#pragma unroll
      for (int ni = 0; ni < 4; ni++) {
        size_t col = n0 + wn + ni * 16 + l15;
        float v = acc[mi][ni][r];
        if (OUT_F16)
          ((ushort*)Cv)[row * N + col] = f32_to_h_bits(v);
        else
          ((float*)Cv)[row * N + col] = v;
      }
    }
  }
}

// ------------------------------------------------------------ flash attention
// qkv: [B*S, 3072] f16 (q|k|v each 1024, head h = cols h*64..h*64+63)
// attn_out: [B*S, 1024] f16.
// Block = (64 q-rows, one (b,h)); 4 waves x 16 q-rows; iterate 64-key tiles.
__global__ __launch_bounds__(256) void attn_fused(const ushort* __restrict__ qkv,
                                                  ushort* __restrict__ attn_out) {
  __shared__ ushort Ks[64 * 72];      // [key][dh], stride 72 breaks 128B bank period
  __shared__ ushort Vt[64 * 66];      // [dh][key], stride 66 -> odd dword stride
  __shared__ ushort Ps[4][16 * 72];   // per-wave P round-trip, stride 72

  const int tid = threadIdx.x;
  const int lane = tid & 63;
  const int w = tid >> 6;
  const int l15 = lane & 15;
  const int quad = lane >> 4;
  const int qt = (int)gridDim.x - 1 - (int)blockIdx.x;  // big tiles launch first
  const int bh = blockIdx.y;
  const int b = bh >> 4;
  const int h = bh & 15;
  const int bS = b * 2048;
  const int qw0 = qt * 64 + w * 16;

  // Q A-frags (k-chunks 0..31, 32..63 of Dh)
  U4H8 qf[2];
  {
    const ushort* qrow = qkv + (size_t)(bS + qw0 + l15) * 3072 + h * 64;
    qf[0].u = *(const uint4*)(qrow + quad * 8);
    qf[1].u = *(const uint4*)(qrow + 32 + quad * 8);
  }

  floatx4 o[4];
#pragma unroll
  for (int ni = 0; ni < 4; ni++) o[ni] = (floatx4){0.f, 0.f, 0.f, 0.f};
  float m_i[4], l_i[4];
#pragma unroll
  for (int r = 0; r < 4; r++) { m_i[r] = -1e30f; l_i[r] = 0.f; }

  const int r0 = tid >> 3;        // staging: key row 0..31 (+32)
  const int c0 = (tid & 7) * 8;   // dh chunk
  const ushort* kbase = qkv + (size_t)bS * 3072 + 1024 + h * 64;
  const ushort* vbase = qkv + (size_t)bS * 3072 + 2048 + h * 64;

  for (int kt = 0; kt <= qt; kt++) {
    __syncthreads();  // previous tile fully consumed before restage
    {
      uint4 k0 = *(const uint4*)(kbase + (size_t)(kt * 64 + r0) * 3072 + c0);
      uint4 k1 = *(const uint4*)(kbase + (size_t)(kt * 64 + r0 + 32) * 3072 + c0);
      uint4 v0 = *(const uint4*)(vbase + (size_t)(kt * 64 + r0) * 3072 + c0);
      uint4 v1 = *(const uint4*)(vbase + (size_t)(kt * 64 + r0 + 32) * 3072 + c0);
      *(uint4*)&Ks[r0 * 72 + c0] = k0;
      *(uint4*)&Ks[(r0 + 32) * 72 + c0] = k1;
      union { uint4 u; ushort s[8]; } vv0, vv1;
      vv0.u = v0; vv1.u = v1;
#pragma unroll
      for (int j = 0; j < 8; j++) {  // transpose into Vt
        Vt[(c0 + j) * 66 + r0] = vv0.s[j];
        Vt[(c0 + j) * 66 + r0 + 32] = vv1.s[j];
      }
    }
    __syncthreads();

    // ---- S = Q K^T for 4 16-key subtiles (skip fully-masked ones)
    floatx4 s4[4];
#pragma unroll
    for (int t16 = 0; t16 < 4; t16++) s4[t16] = (floatx4){-1e30f, -1e30f, -1e30f, -1e30f};
    const int n16 = min(4, ((qw0 - kt * 64) >> 4) + 1);  // wave-uniform, >=1
    for (int t16 = 0; t16 < n16; t16++) {
      U4H8 kf0, kf1;
      kf0.u = *(const uint4*)&Ks[(t16 * 16 + l15) * 72 + quad * 8];
      kf1.u = *(const uint4*)&Ks[(t16 * 16 + l15) * 72 + 32 + quad * 8];
      floatx4 sa = (floatx4){0.f, 0.f, 0.f, 0.f};
      sa = __builtin_amdgcn_mfma_f32_16x16x32_f16(qf[0].h, kf0.h, sa, 0, 0, 0);
      sa = __builtin_amdgcn_mfma_f32_16x16x32_f16(qf[1].h, kf1.h, sa, 0, 0, 0);
      const int key = kt * 64 + t16 * 16 + l15;
#pragma unroll
      for (int r = 0; r < 4; r++) {
        int q = qw0 + quad * 4 + r;
        s4[t16][r] = (key <= q) ? sa[r] * 0.125f : -1e30f;  // scale 1/sqrt(64)
      }
    }

    // ---- online softmax (row stats across 16 cols = lane bits 0..3)
    float alpha[4];
#pragma unroll
    for (int r = 0; r < 4; r++) {
      float tmax = fmaxf(fmaxf(s4[0][r], s4[1][r]), fmaxf(s4[2][r], s4[3][r]));
      tmax = fmaxf(tmax, __shfl_xor(tmax, 1));
      tmax = fmaxf(tmax, __shfl_xor(tmax, 2));
      tmax = fmaxf(tmax, __shfl_xor(tmax, 4));
      tmax = fmaxf(tmax, __shfl_xor(tmax, 8));
      float mnew = fmaxf(m_i[r], tmax);
      alpha[r] = __expf(m_i[r] - mnew);
      m_i[r] = mnew;
      float rs = 0.f;
#pragma unroll
      for (int t16 = 0; t16 < 4; t16++) {
        float p = __expf(s4[t16][r] - mnew);  // masked -> exp(-huge)=0
        s4[t16][r] = p;
        rs += p;
      }
      rs += __shfl_xor(rs, 1);
      rs += __shfl_xor(rs, 2);
      rs += __shfl_xor(rs, 4);
      rs += __shfl_xor(rs, 8);
      l_i[r] = l_i[r] * alpha[r] + rs;
    }
#pragma unroll
    for (int ni = 0; ni < 4; ni++)
#pragma unroll
      for (int r = 0; r < 4; r++) o[ni][r] *= alpha[r];

    // ---- P: C-layout -> LDS row-major [16][64] (A-layout source)
#pragma unroll
    for (int t16 = 0; t16 < 4; t16++)
#pragma unroll
      for (int r = 0; r < 4; r++)
        Ps[w][(quad * 4 + r) * 72 + t16 * 16 + l15] = f32_to_h_bits(s4[t16][r]);
    __syncthreads();  // cross-lane LDS RAW within wave; block barrier is safe & uniform

    // ---- O += P V
    U4H8 pa0, pa1;
    pa0.u = *(const uint4*)&Ps[w][l15 * 72 + quad * 8];
    pa1.u = *(const uint4*)&Ps[w][l15 * 72 + 32 + quad * 8];
#pragma unroll
    for (int ni = 0; ni < 4; ni++) {
#pragma unroll
      for (int kc = 0; kc < 2; kc++) {
        union { uint u[4]; f16x8 h; } vf;
        const ushort* vp = &Vt[(ni * 16 + l15) * 66 + kc * 32 + quad * 8];
#pragma unroll
        for (int jj = 0; jj < 4; jj++) vf.u[jj] = *(const uint*)(vp + jj * 2);
        o[ni] = __builtin_amdgcn_mfma_f32_16x16x32_f16(kc == 0 ? pa0.h : pa1.h,
                                                       vf.h, o[ni], 0, 0, 0);
      }
    }
  }

  // ---- epilogue: attn_out[b*S+q][h*64+dh] = o / l
#pragma unroll
  for (int r = 0; r < 4; r++) {
    float inv = 1.0f / l_i[r];
    int q = qw0 + quad * 4 + r;
    ushort* orow = attn_out + (size_t)(bS + q) * 1024 + h * 64;
#pragma unroll
    for (int ni = 0; ni < 4; ni++) orow[ni * 16 + l15] = f32_to_h_bits(o[ni][r] * inv);
  }
}

// ---------------------------------------------------------------------- launch
extern "C" void kernel_launch(void* const* d_in, const int* in_sizes, int n_in,
                              void* d_out, int out_size, void* d_ws, size_t ws_size,
                              hipStream_t stream) {
  const float* x = (const float*)d_in[0];       // [4,2048,1024]
  const float* wqkv = (const float*)d_in[1];    // [3072,1024]
  const float* wo = (const float*)d_in[2];      // [1024,1024]
  float* out = (float*)d_out;                   // [4,2048,1024] fp32

  ushort* xh = (ushort*)d_ws;                          // 8192*1024
  ushort* wqkvh = xh + (size_t)8192 * 1024;            // 3072*1024
  ushort* woh = wqkvh + (size_t)3072 * 1024;           // 1024*1024
  ushort* qkvh = woh + (size_t)1024 * 1024;            // 8192*3072
  ushort* attnh = qkvh + (size_t)8192 * 3072;          // 8192*1024
  // total ws use: ~92 MB

  cast_f32_f16<<<8192, 256, 0, stream>>>(x, xh);       // 8.4M elems
  cast_f32_f16<<<3072, 256, 0, stream>>>(wqkv, wqkvh); // 3.1M
  cast_f32_f16<<<1024, 256, 0, stream>>>(wo, woh);     // 1.0M

  gemm_bt<1><<<dim3(24, 64), 256, 0, stream>>>(xh, wqkvh, qkvh, 8192, 3072, 1024);
  attn_fused<<<dim3(32, 64), 256, 0, stream>>>(qkvh, attnh);
  gemm_bt<0><<<dim3(8, 64), 256, 0, stream>>>(attnh, woh, out, 8192, 1024, 1024);
}